// Round 5
// baseline (255.267 us; speedup 1.0000x reference)
//
#include <hip/hip_runtime.h>
#include <cstdint>

constexpr int D = 256;

typedef __bf16 bf16x8  __attribute__((ext_vector_type(8)));
typedef float  f32x16  __attribute__((ext_vector_type(16)));

// ---- prep 1: W2 = W (fp32), b2 = b ------------------------------------
__global__ void prep_copy(const float* __restrict__ W, const float* __restrict__ b,
                          float* __restrict__ W2, float* __restrict__ b2) {
    int i = blockIdx.x * 256 + threadIdx.x;
    W2[i] = W[i];
    if (blockIdx.x == 0) b2[threadIdx.x] = b[threadIdx.x];
}

// ---- prep 2: per edge e: W2[dst,:] += W[src,:]; b2[dst] += b[src] ------
__global__ void prep_edges(const int* __restrict__ em, int E,
                           const float* __restrict__ W, const float* __restrict__ b,
                           float* __restrict__ W2, float* __restrict__ b2) {
    int e = blockIdx.x;
    int k = threadIdx.x;
    int dst = em[e];
    int src = em[E + e];
    atomicAdd(&W2[dst * D + k], W[src * D + k]);
    if (k == 0) atomicAdd(&b2[dst], b[src]);
}

// ---- prep 3: W2 fp32 -> RNE bf16, 32x32x16 B-frag order ----------------
// B-frag: lane holds B[o = ob32*32 + (lane&31)][k = ks*16 + (lane>>5)*8 + j]
// idx = ((ks*8 + ob32)*64 + lane)*8 + j   (each (ks,ob32) chunk = 1 KB contig)
__global__ void prep_convert(const float* __restrict__ W2, ushort* __restrict__ Wh) {
    int i = blockIdx.x * 256 + threadIdx.x;   // i = o*256 + k
    int o = i >> 8, k = i & 255;
    uint32_t u = __float_as_uint(W2[i]);
    uint32_t r = u + 0x7FFFu + ((u >> 16) & 1u);   // RNE to bf16
    int ks = k >> 4, kh = (k >> 3) & 1, j = k & 7;
    int lane = (o & 31) + 32 * kh;
    int idx = ((ks * 8 + (o >> 5)) * 64 + lane) * 8 + j;
    Wh[idx] = (ushort)(r >> 16);
}

// ---- cheap fp32x8 -> bf16 hi(trunc) / lo(trunc of exact residual) ------
// 3 VALU/elem: v_and, v_sub, shared v_perm pack.
__device__ __forceinline__ void cvt8p(const float4& f0, const float4& f1,
                                      bf16x8& hi8, bf16x8& lo8) {
    float xs[8] = {f0.x, f0.y, f0.z, f0.w, f1.x, f1.y, f1.z, f1.w};
    uint32_t hp[4], lp[4];
    #pragma unroll
    for (int j = 0; j < 4; ++j) {
        uint32_t u0 = __float_as_uint(xs[2 * j]);
        uint32_t u1 = __float_as_uint(xs[2 * j + 1]);
        uint32_t h0 = u0 & 0xFFFF0000u;
        uint32_t h1 = u1 & 0xFFFF0000u;
        float r0 = xs[2 * j]     - __uint_as_float(h0);
        float r1 = xs[2 * j + 1] - __uint_as_float(h1);
        hp[j] = __builtin_amdgcn_perm(h1, h0, 0x07060302u);
        lp[j] = __builtin_amdgcn_perm(__float_as_uint(r1), __float_as_uint(r0), 0x07060302u);
    }
    uint4 h4 = make_uint4(hp[0], hp[1], hp[2], hp[3]);
    uint4 l4 = make_uint4(lp[0], lp[1], lp[2], lp[3]);
    hi8 = *(bf16x8*)&h4;
    lo8 = *(bf16x8*)&l4;
}

// ---- main GEMM: no LDS, no barriers, PF-2 pipeline, 32x32x16 MFMA ------
// Block = 4 waves stacked in m (m-128 x o-64). Wave = m-32 x o-64.
// acc: 2 x f32x16 = 32 AGPRs. X: 3-slot reg buffer (prefetch distance 2).
// B (bf16 frag-order, L2-resident): 2-slot buffer (distance 1).
__global__ __launch_bounds__(256) void resgcn_mfma(
    const float* __restrict__ X, const ushort* __restrict__ Whg,
    const float* __restrict__ b2, const float* __restrict__ blen,
    float* __restrict__ out, int M)
{
    const int tid  = threadIdx.x;
    const int lane = tid & 63;
    const int w    = tid >> 6;
    const int bid  = blockIdx.x;
    const int oc   = bid & 3;          // o 64-column
    const int mb   = bid >> 2;

    const int m0 = mb * 128 + w * 32;
    int row = m0 + (lane & 31);
    if (row >= M) row = M - 1;                     // clamp: real data, no NaN
    const int kh = lane >> 5;                      // k-half of A/B frag
    const float* xp = X + (size_t)row * D + kh * 8;

    // B chunk (ks, ob): 1 KB contiguous per wave
    const ushort* bp = Whg + (size_t)(oc * 2) * 512 + lane * 8;

    f32x16 acc[2];
    acc[0] = (f32x16)(0.f);
    acc[1] = (f32x16)(0.f);

    float4 xb[3][4];   // [slot][s*2 + half]: s = k16-step in chunk, half = float4 of 8
    bf16x8 bb[2][4];   // [slot][s*2 + ob]

    #define LOAD_X(kc, slot)                                                  \
        { const float* p = xp + (kc) * 32;                                    \
          xb[slot][0] = *(const float4*)(p);                                  \
          xb[slot][1] = *(const float4*)(p + 4);                              \
          xb[slot][2] = *(const float4*)(p + 16);                             \
          xb[slot][3] = *(const float4*)(p + 20); }
    #define LOAD_B(kc, slot)                                                  \
        { const ushort* q = bp + (size_t)(kc) * 2 * 8 * 512;                  \
          bb[slot][0] = *(const bf16x8*)(q);                                  \
          bb[slot][1] = *(const bf16x8*)(q + 512);                            \
          bb[slot][2] = *(const bf16x8*)(q + 8 * 512);                        \
          bb[slot][3] = *(const bf16x8*)(q + 9 * 512); }

    LOAD_X(0, 0)
    LOAD_X(1, 1)
    LOAD_B(0, 0)

    #pragma unroll
    for (int kc = 0; kc < 8; ++kc) {
        const int cur3 = kc % 3;
        const int cur2 = kc & 1;
        if (kc + 2 < 8) LOAD_X(kc + 2, (kc + 2) % 3)
        if (kc + 1 < 8) LOAD_B(kc + 1, (kc + 1) & 1)

        bf16x8 ah[2], al[2];
        cvt8p(xb[cur3][0], xb[cur3][1], ah[0], al[0]);
        cvt8p(xb[cur3][2], xb[cur3][3], ah[1], al[1]);

        #pragma unroll
        for (int s = 0; s < 2; ++s)
            #pragma unroll
            for (int ob = 0; ob < 2; ++ob) {
                acc[ob] = __builtin_amdgcn_mfma_f32_32x32x16_bf16(
                              ah[s], bb[cur2][s * 2 + ob], acc[ob], 0, 0, 0);
                acc[ob] = __builtin_amdgcn_mfma_f32_32x32x16_bf16(
                              al[s], bb[cur2][s * 2 + ob], acc[ob], 0, 0, 0);
            }
    }
    #undef LOAD_X
    #undef LOAD_B

    // epilogue: C/D layout col = lane&31, row = (r&3) + 8*(r>>2) + 4*(lane>>5)
    const int col = lane & 31;
    float inv16[16];
    #pragma unroll
    for (int r = 0; r < 16; ++r) {
        int m = m0 + (r & 3) + 8 * (r >> 2) + 4 * kh;
        inv16[r] = 1.0f / blen[(m < M) ? m : (M - 1)];
    }
    #pragma unroll
    for (int ob = 0; ob < 2; ++ob) {
        int o = oc * 64 + ob * 32 + col;
        float bias = b2[o];
        #pragma unroll
        for (int r = 0; r < 16; ++r) {
            int m = m0 + (r & 3) + 8 * (r >> 2) + 4 * kh;
            if (m < M)
                out[(size_t)m * D + o] = (acc[ob][r] + bias) * inv16[r];
        }
    }
}

extern "C" void kernel_launch(void* const* d_in, const int* in_sizes, int n_in,
                              void* d_out, int out_size, void* d_ws, size_t ws_size,
                              hipStream_t stream) {
    (void)n_in; (void)out_size; (void)ws_size;
    const float* X  = (const float*)d_in[0];
    const float* W  = (const float*)d_in[1];
    const float* b  = (const float*)d_in[2];
    const int*   em = (const int*)d_in[3];
    const float* bl = (const float*)d_in[4];
    float* out = (float*)d_out;

    const int M = in_sizes[0] / D;
    const int E = in_sizes[3] / 2;

    float*  W2 = (float*)d_ws;           // 65536 fp32
    float*  b2 = W2 + D * D;             // 256 fp32
    ushort* Wh = (ushort*)(b2 + D);      // 65536 bf16, 32x32 frag-ordered

    prep_copy<<<D * D / 256, 256, 0, stream>>>(W, b, W2, b2);
    prep_edges<<<E, D, 0, stream>>>(em, E, W, b, W2, b2);
    prep_convert<<<D * D / 256, 256, 0, stream>>>(W2, Wh);

    int mblocks = (M + 127) / 128;
    resgcn_mfma<<<mblocks * 4, 256, 0, stream>>>(X, Wh, b2, bl, out, M);
}